// Round 9
// baseline (339.687 us; speedup 1.0000x reference)
//
#include <hip/hip_runtime.h>
#include <hip/hip_bf16.h>
#include <stdint.h>

// MHA: B=2, S=2048, D=1024, H=16, dk=64.  All GEMM-shaped work in bf16 MFMA.
// conv->bf16 | QKV gemm (LOG2E/8 in Wq,bq; V transposed [bh][d][s]) |
// flash attn 32x32x16, in-register P (cvt_pk+permlane), no-max softmax,
// KEY-SPLIT x2 ACROSS GRID (blockIdx.z): 256-thd blocks keep VGPR~100 (r8's
// in-block split spilled at the 128-reg cap); partial o (f32) + l combined
// by atomicAdd (exactly 2 adds/element -> commutative -> deterministic) |
// O-proj gemm with 1/l normalization fused into A-staging -> f32 out.

#define LOG2E 1.4426950408889634f

typedef float f32x4 __attribute__((ext_vector_type(4)));
typedef float f32x16 __attribute__((ext_vector_type(16)));
typedef short bf16x8 __attribute__((ext_vector_type(8)));
typedef short bf16x4 __attribute__((ext_vector_type(4)));
typedef unsigned int u32x2 __attribute__((ext_vector_type(2)));

__device__ __forceinline__ unsigned short f2bf(float f) {
  __hip_bfloat16 h = __float2bfloat16(f);
  return reinterpret_cast<unsigned short&>(h);
}

#define GLDS(g, l) __builtin_amdgcn_global_load_lds(                          \
    (const __attribute__((address_space(1))) void*)(g),                       \
    (__attribute__((address_space(3))) void*)(l), 16, 0, 0)

// ---------- fp32 -> bf16 conversion ----------
__global__ __launch_bounds__(256) void k_conv(const float* __restrict__ src,
                                              unsigned short* __restrict__ dst,
                                              int n4, float scale) {
  int i = blockIdx.x * 256 + threadIdx.x;
  const int stride = gridDim.x * 256;
  for (; i < n4; i += stride) {
    float4 v = ((const float4*)src)[i];
    ushort4 o;
    o.x = f2bf(v.x * scale);
    o.y = f2bf(v.y * scale);
    o.z = f2bf(v.z * scale);
    o.w = f2bf(v.w * scale);
    ((ushort4*)dst)[i] = o;
  }
}

// all 4 weight matrices in one launch; Wq scaled by LOG2E/8
__global__ __launch_bounds__(256) void k_convW(const float* __restrict__ wq,
                                               const float* __restrict__ wk,
                                               const float* __restrict__ wv,
                                               const float* __restrict__ wo,
                                               unsigned short* __restrict__ dq,
                                               unsigned short* __restrict__ dk,
                                               unsigned short* __restrict__ dv,
                                               unsigned short* __restrict__ dw) {
  const int m = blockIdx.y;
  const float* src = (m == 0) ? wq : (m == 1) ? wk : (m == 2) ? wv : wo;
  unsigned short* dst = (m == 0) ? dq : (m == 1) ? dk : (m == 2) ? dv : dw;
  const float scale = (m == 0) ? (0.125f * LOG2E) : 1.0f;
  int i = blockIdx.x * 256 + threadIdx.x;
  float4 v = ((const float4*)src)[i];
  ushort4 o;
  o.x = f2bf(v.x * scale);
  o.y = f2bf(v.y * scale);
  o.z = f2bf(v.z * scale);
  o.w = f2bf(v.w * scale);
  ((ushort4*)dst)[i] = o;
}

// fused bias vector [3072]: bq*LOG2E/8 | bk | bv
__global__ __launch_bounds__(256) void k_bias(const float* __restrict__ bq,
                                              const float* __restrict__ bk,
                                              const float* __restrict__ bv,
                                              float* __restrict__ out) {
  int i = blockIdx.x * 256 + threadIdx.x;
  float v;
  if (i < 1024) v = bq[i] * (0.125f * LOG2E);
  else if (i < 2048) v = bk[i - 1024];
  else v = bv[i - 2048];
  out[i] = v;
}

// ---------- QKV GEMM: C[m][n] = sum_k A[m][k]*B[n][k] + bias[n] ----------
__global__ __launch_bounds__(256) void k_gemm0(const unsigned short* __restrict__ A,
                                               const unsigned short* __restrict__ B,
                                               const float* __restrict__ bias,
                                               unsigned short* __restrict__ outp) {
  __shared__ unsigned short As[128 * 32];
  __shared__ unsigned short Bs[128 * 32];
  const int tid = threadIdx.x;
  const int lane = tid & 63, wid = tid >> 6;
  const int wr = wid >> 1, wc = wid & 1;
  const int r = lane & 15, g = lane >> 4;
  const int bm = blockIdx.x, bn = blockIdx.y;

  const unsigned short* gA = A + (size_t)bm * 128 * 1024;
  const unsigned short* gB = B + (size_t)bn * 128 * 1024;
  const int row0 = tid >> 2, cg = (tid & 3) * 8;

  f32x4 acc[4][4] = {};

  for (int k0 = 0; k0 < 1024; k0 += 32) {
    __syncthreads();
    GLDS(gA + (size_t)row0 * 1024 + k0 + cg,        As + row0 * 32 + cg);
    GLDS(gA + (size_t)(row0 + 64) * 1024 + k0 + cg, As + (row0 + 64) * 32 + cg);
    GLDS(gB + (size_t)row0 * 1024 + k0 + cg,        Bs + row0 * 32 + cg);
    GLDS(gB + (size_t)(row0 + 64) * 1024 + k0 + cg, Bs + (row0 + 64) * 32 + cg);
    __syncthreads();

    bf16x8 af[4], bfr[4];
#pragma unroll
    for (int i = 0; i < 4; i++) {
      af[i]  = *(const bf16x8*)(As + (wr * 64 + i * 16 + r) * 32 + g * 8);
      bfr[i] = *(const bf16x8*)(Bs + (wc * 64 + i * 16 + r) * 32 + g * 8);
    }
#pragma unroll
    for (int i = 0; i < 4; i++)
#pragma unroll
      for (int j = 0; j < 4; j++)
        acc[i][j] = __builtin_amdgcn_mfma_f32_16x16x32_bf16(af[i], bfr[j], acc[i][j], 0, 0, 0);
  }

#pragma unroll
  for (int i = 0; i < 4; i++) {
    const int rowb = bm * 128 + wr * 64 + i * 16 + g * 4;
#pragma unroll
    for (int j = 0; j < 4; j++) {
      const int col = bn * 128 + wc * 64 + j * 16 + r;
      const float bv = bias[col];
#pragma unroll
      for (int t = 0; t < 4; t++) {
        const int row = rowb + t;
        const float val = acc[i][j][t] + bv;
        const int mat = col >> 10, nn = col & 1023;
        const int hh = nn >> 6, dd = nn & 63;
        const int bb = row >> 11, ss = row & 2047;
        size_t idx;
        if (mat == 2)  // V transposed: [bh][d][s]
          idx = (size_t)2 * 4194304 + (size_t)((bb * 16 + hh) * 64 + dd) * 2048 + ss;
        else
          idx = (size_t)mat * 4194304 + (size_t)((bb * 16 + hh) * 2048 + ss) * 64 + dd;
        outp[idx] = f2bf(val);
      }
    }
  }
}

// ---------- O-proj GEMM: A = mrgF(f32, unnormalized) * (1/l) cvt bf16 ------
// out[row][col] = sum_k (mrgF[row][k]/l[b,h(k),s]) * Wo[col][k] + bo[col]
__global__ __launch_bounds__(256) void k_gemm1(const float* __restrict__ A,
                                               const float* __restrict__ lG,
                                               const unsigned short* __restrict__ Bw,
                                               const float* __restrict__ bias,
                                               float* __restrict__ outp) {
  __shared__ unsigned short As[128 * 32];
  __shared__ unsigned short Bs[128 * 32];
  const int tid = threadIdx.x;
  const int lane = tid & 63, wid = tid >> 6;
  const int wr = wid >> 1, wc = wid & 1;
  const int r = lane & 15, g = lane >> 4;
  const int bm = blockIdx.x, bn = blockIdx.y;

  const unsigned short* gB = Bw + (size_t)bn * 128 * 1024;
  const int row0 = tid >> 2, cg = (tid & 3) * 8;
  const int gr0 = bm * 128 + row0, gr1 = gr0 + 64;
  const int s0g = gr0 & 2047, b0g = gr0 >> 11;
  const int s1g = gr1 & 2047, b1g = gr1 >> 11;

  f32x4 acc[4][4] = {};

  for (int k0 = 0; k0 < 1024; k0 += 32) {
    const int hh = (k0 + cg) >> 6;
    const float li0 = 1.0f / lG[(b0g * 16 + hh) * 2048 + s0g];
    const float li1 = 1.0f / lG[(b1g * 16 + hh) * 2048 + s1g];
    const float4 a00 = *(const float4*)(A + (size_t)gr0 * 1024 + k0 + cg);
    const float4 a01 = *(const float4*)(A + (size_t)gr0 * 1024 + k0 + cg + 4);
    const float4 a10 = *(const float4*)(A + (size_t)gr1 * 1024 + k0 + cg);
    const float4 a11 = *(const float4*)(A + (size_t)gr1 * 1024 + k0 + cg + 4);
    __syncthreads();
    GLDS(gB + (size_t)row0 * 1024 + k0 + cg,        Bs + row0 * 32 + cg);
    GLDS(gB + (size_t)(row0 + 64) * 1024 + k0 + cg, Bs + (row0 + 64) * 32 + cg);
    bf16x8 pa0, pa1;
    pa0[0] = f2bf(a00.x * li0); pa0[1] = f2bf(a00.y * li0);
    pa0[2] = f2bf(a00.z * li0); pa0[3] = f2bf(a00.w * li0);
    pa0[4] = f2bf(a01.x * li0); pa0[5] = f2bf(a01.y * li0);
    pa0[6] = f2bf(a01.z * li0); pa0[7] = f2bf(a01.w * li0);
    pa1[0] = f2bf(a10.x * li1); pa1[1] = f2bf(a10.y * li1);
    pa1[2] = f2bf(a10.z * li1); pa1[3] = f2bf(a10.w * li1);
    pa1[4] = f2bf(a11.x * li1); pa1[5] = f2bf(a11.y * li1);
    pa1[6] = f2bf(a11.z * li1); pa1[7] = f2bf(a11.w * li1);
    *(bf16x8*)(As + row0 * 32 + cg) = pa0;
    *(bf16x8*)(As + (row0 + 64) * 32 + cg) = pa1;
    __syncthreads();

    bf16x8 af[4], bfr[4];
#pragma unroll
    for (int i = 0; i < 4; i++) {
      af[i]  = *(const bf16x8*)(As + (wr * 64 + i * 16 + r) * 32 + g * 8);
      bfr[i] = *(const bf16x8*)(Bs + (wc * 64 + i * 16 + r) * 32 + g * 8);
    }
#pragma unroll
    for (int i = 0; i < 4; i++)
#pragma unroll
      for (int j = 0; j < 4; j++)
        acc[i][j] = __builtin_amdgcn_mfma_f32_16x16x32_bf16(af[i], bfr[j], acc[i][j], 0, 0, 0);
  }

#pragma unroll
  for (int i = 0; i < 4; i++) {
    const int rowb = bm * 128 + wr * 64 + i * 16 + g * 4;
#pragma unroll
    for (int j = 0; j < 4; j++) {
      const int col = bn * 128 + wc * 64 + j * 16 + r;
      const float bv = bias[col];
#pragma unroll
      for (int t = 0; t < 4; t++)
        outp[(size_t)(rowb + t) * 1024 + col] = acc[i][j][t] + bv;
    }
  }
}

// ---------- flash attention (32x32 MFMA, grid key-split x2) ----------
// grid (16 q-tiles of 128, 32 b*h, 2 key-halves), 256 threads = 4 waves.
// Wave w owns q-rows q0+w*32+(lane&31); this block covers keys kg*1024..+1023
// (16 tiles of 64).  Per 32-key subtile: 4 QK MFMA -> 16 exp2 -> 8 cvt_pk +
// 4 permlane32_swap (in-reg P B-frags) -> 4 PV MFMA.  Epilogue: atomicAdd
// raw o (f32) and l into zeroed buffers (2 adds/elem, commutative -> exact).
__global__ __launch_bounds__(256) void k_attn(const unsigned short* __restrict__ Q,
                                              const unsigned short* __restrict__ Km,
                                              const unsigned short* __restrict__ Vt,
                                              float* __restrict__ mrgF,
                                              float* __restrict__ lG) {
  __shared__ unsigned short Kb[2][4096];
  __shared__ unsigned short Vb[2][4096];
  const int tid = threadIdx.x;
  const int lane = tid & 63, w = tid >> 6;
  const int l31 = lane & 31, hi = lane >> 5;
  const int bh = blockIdx.y;
  const int b = bh >> 4, h = bh & 15;
  const int q0 = blockIdx.x * 128;
  const int kg = blockIdx.z;

  const unsigned short* Qh  = Q  + (size_t)bh * 131072;                        // [s][d]
  const unsigned short* KhG = Km + (size_t)bh * 131072 + (size_t)kg * 65536;   // [s][d]
  const unsigned short* VtG = Vt + (size_t)bh * 131072 + 1024 * kg;            // [d][s]

  const int qrow = q0 + w * 32 + l31;
  bf16x8 bQ[4];
#pragma unroll
  for (int c = 0; c < 4; c++)
    bQ[c] = *(const bf16x8*)(Qh + (size_t)qrow * 64 + c * 16 + hi * 8);

  // staging source perms (chunk id = op*256+tid -> (s, c, l2))
  int ksrc[2], vsrc[2];
#pragma unroll
  for (int op = 0; op < 2; op++) {
    const int ck = op * 256 + tid;
    const int s = ck >> 8, c = (ck >> 6) & 3, l2 = ck & 63;
    ksrc[op] = (s * 32 + (l2 & 31)) * 64 + c * 16 + (l2 >> 5) * 8;
    vsrc[op] = (s * 32 + (l2 & 31)) * 2048 + c * 16 + (l2 >> 5) * 8;
  }
  const int ldst = tid * 8;

  GLDS(KhG + ksrc[0], &Kb[0][ldst]);
  GLDS(KhG + ksrc[1], &Kb[0][2048 + ldst]);
  GLDS(VtG + vsrc[0], &Vb[0][ldst]);
  GLDS(VtG + vsrc[1], &Vb[0][2048 + ldst]);
  __syncthreads();

  f32x16 o0 = {0.f,0.f,0.f,0.f,0.f,0.f,0.f,0.f,0.f,0.f,0.f,0.f,0.f,0.f,0.f,0.f};
  f32x16 o1 = o0;
  float lsum = 0.f;

  for (int t = 0; t < 16; ++t) {
    const int cur = t & 1;
    if (t < 15) {
      const size_t kv = (size_t)(t + 1) * 64;
      GLDS(KhG + kv * 64 + ksrc[0], &Kb[cur ^ 1][ldst]);
      GLDS(KhG + kv * 64 + ksrc[1], &Kb[cur ^ 1][2048 + ldst]);
      GLDS(VtG + kv + vsrc[0], &Vb[cur ^ 1][ldst]);
      GLDS(VtG + kv + vsrc[1], &Vb[cur ^ 1][2048 + ldst]);
    }

    const unsigned short* kb = &Kb[cur][0];
    const unsigned short* vb = &Vb[cur][0];

#define SUBTILE(SC)                                                            \
    {                                                                          \
      bf16x8 kf0 = *(const bf16x8*)(kb + (((SC)*4 + 0) * 64 + lane) * 8);      \
      bf16x8 kf1 = *(const bf16x8*)(kb + (((SC)*4 + 1) * 64 + lane) * 8);      \
      bf16x8 kf2 = *(const bf16x8*)(kb + (((SC)*4 + 2) * 64 + lane) * 8);      \
      bf16x8 kf3 = *(const bf16x8*)(kb + (((SC)*4 + 3) * 64 + lane) * 8);      \
      f32x16 St = {0.f,0.f,0.f,0.f,0.f,0.f,0.f,0.f,                            \
                   0.f,0.f,0.f,0.f,0.f,0.f,0.f,0.f};                           \
      St = __builtin_amdgcn_mfma_f32_32x32x16_bf16(kf0, bQ[0], St, 0, 0, 0);   \
      St = __builtin_amdgcn_mfma_f32_32x32x16_bf16(kf1, bQ[1], St, 0, 0, 0);   \
      St = __builtin_amdgcn_mfma_f32_32x32x16_bf16(kf2, bQ[2], St, 0, 0, 0);   \
      St = __builtin_amdgcn_mfma_f32_32x32x16_bf16(kf3, bQ[3], St, 0, 0, 0);   \
      float p[16];                                                             \
      float ps = 0.f;                                                          \
      _Pragma("unroll")                                                        \
      for (int u = 0; u < 16; u++) {                                           \
        p[u] = __builtin_amdgcn_exp2f(St[u]);                                  \
        ps += p[u];                                                            \
      }                                                                        \
      lsum += ps;                                                              \
      unsigned int a0, a1, b0, b1;                                             \
      asm("v_cvt_pk_bf16_f32 %0, %1, %2" : "=v"(a0) : "v"(p[0]), "v"(p[1]));   \
      asm("v_cvt_pk_bf16_f32 %0, %1, %2" : "=v"(a1) : "v"(p[2]), "v"(p[3]));   \
      asm("v_cvt_pk_bf16_f32 %0, %1, %2" : "=v"(b0) : "v"(p[4]), "v"(p[5]));   \
      asm("v_cvt_pk_bf16_f32 %0, %1, %2" : "=v"(b1) : "v"(p[6]), "v"(p[7]));   \
      u32x2 r0 = __builtin_amdgcn_permlane32_swap(a0, b0, false, false);       \
      u32x2 r1 = __builtin_amdgcn_permlane32_swap(a1, b1, false, false);       \
      union { unsigned int u[4]; bf16x8 v; } pfE;                              \
      pfE.u[0] = r0[0]; pfE.u[1] = r1[0]; pfE.u[2] = r0[1]; pfE.u[3] = r1[1];  \
      asm("v_cvt_pk_bf16_f32 %0, %1, %2" : "=v"(a0) : "v"(p[8]), "v"(p[9]));   \
      asm("v_cvt_pk_bf16_f32 %0, %1, %2" : "=v"(a1) : "v"(p[10]), "v"(p[11])); \
      asm("v_cvt_pk_bf16_f32 %0, %1, %2" : "=v"(b0) : "v"(p[12]), "v"(p[13])); \
      asm("v_cvt_pk_bf16_f32 %0, %1, %2" : "=v"(b1) : "v"(p[14]), "v"(p[15])); \
      r0 = __builtin_amdgcn_permlane32_swap(a0, b0, false, false);             \
      r1 = __builtin_amdgcn_permlane32_swap(a1, b1, false, false);             \
      union { unsigned int u[4]; bf16x8 v; } pfO;                              \
      pfO.u[0] = r0[0]; pfO.u[1] = r1[0]; pfO.u[2] = r0[1]; pfO.u[3] = r1[1];  \
      bf16x8 v00 = *(const bf16x8*)(vb + ((0 + 2*(SC)) * 64 + lane) * 8);      \
      bf16x8 v01 = *(const bf16x8*)(vb + ((1 + 2*(SC)) * 64 + lane) * 8);      \
      bf16x8 v10 = *(const bf16x8*)(vb + ((4 + 2*(SC)) * 64 + lane) * 8);      \
      bf16x8 v11 = *(const bf16x8*)(vb + ((5 + 2*(SC)) * 64 + lane) * 8);      \
      o0 = __builtin_amdgcn_mfma_f32_32x32x16_bf16(v00, pfE.v, o0, 0, 0, 0);   \
      o0 = __builtin_amdgcn_mfma_f32_32x32x16_bf16(v01, pfO.v, o0, 0, 0, 0);   \
      o1 = __builtin_amdgcn_mfma_f32_32x32x16_bf16(v10, pfE.v, o1, 0, 0, 0);   \
      o1 = __builtin_amdgcn_mfma_f32_32x32x16_bf16(v11, pfO.v, o1, 0, 0, 0);   \
    }

    SUBTILE(0)
    SUBTILE(1)
#undef SUBTILE

    __syncthreads();   // drains stage vmcnt + protects buffer reuse
  }

  // epilogue: atomicAdd partials.  o[ds] reg u -> d = ds*32+(u&3)+8*(u>>2)+4*hi.
  const float lrow = lsum + __shfl_xor(lsum, 32);
  if (hi == 0) atomicAdd(&lG[bh * 2048 + qrow], lrow);
  const size_t base = (size_t)(b * 2048 + qrow) * 1024 + h * 64;
#pragma unroll
  for (int ds = 0; ds < 2; ds++) {
    const f32x16& oo = ds ? o1 : o0;
#pragma unroll
    for (int m = 0; m < 4; m++)
#pragma unroll
      for (int i = 0; i < 4; i++)
        atomicAdd(&mrgF[base + ds * 32 + m * 8 + hi * 4 + i], oo[m * 4 + i]);
  }
}

extern "C" void kernel_launch(void* const* d_in, const int* in_sizes, int n_in,
                              void* d_out, int out_size, void* d_ws, size_t ws_size,
                              hipStream_t stream) {
  const float* x  = (const float*)d_in[0];
  const float* Wq = (const float*)d_in[1];
  const float* bq = (const float*)d_in[2];
  const float* Wk = (const float*)d_in[3];
  const float* bk = (const float*)d_in[4];
  const float* Wv = (const float*)d_in[5];
  const float* bv = (const float*)d_in[6];
  const float* Wo = (const float*)d_in[7];
  const float* bo = (const float*)d_in[8];

  if (ws_size < (size_t)44314624) return;

  unsigned short* ws  = (unsigned short*)d_ws;
  unsigned short* xb  = ws;                // x bf16 [4096][1024]   (dead after gemm0)
  unsigned short* Wb  = ws + 4194304;      // Wq'|Wk|Wv bf16        (dead after gemm0)
  unsigned short* qkv = ws + 8388608;      // Q|K [32][2048][64]; Vt [32][64][2048]
  unsigned short* Wob = ws + 20971520;     // Wo bf16 [1024][1024]
  float* biasQ = (float*)(ws + 22020096);  // fused qkv bias [3072]
  float* lG    = (float*)(ws + 22026240);  // l sums [32][2048]
  float* mrgF  = (float*)ws;               // attn partial-sum f32 [4096][1024]
                                           // (overlays xb+Wb; zeroed after gemm0)

  k_conv<<<dim3(2048), dim3(256), 0, stream>>>(x, xb, 1048576, 1.0f);
  k_convW<<<dim3(1024, 4), dim3(256), 0, stream>>>(Wq, Wk, Wv, Wo,
      Wb, Wb + 1048576, Wb + 2097152, Wob);
  k_bias<<<dim3(12), dim3(256), 0, stream>>>(bq, bk, bv, biasQ);

  k_gemm0<<<dim3(32, 24), dim3(256), 0, stream>>>(xb, Wb, biasQ, qkv);

  hipMemsetAsync(mrgF, 0, (size_t)4194304 * 4, stream);
  hipMemsetAsync(lG, 0, (size_t)65536 * 4, stream);

  k_attn<<<dim3(16, 32, 2), dim3(256), 0, stream>>>(
      qkv, qkv + 4194304, qkv + 8388608, mrgF, lG);
  k_gemm1<<<dim3(32, 8), dim3(256), 0, stream>>>(mrgF, lG, Wob, bo, (float*)d_out);
}

// Round 10
// 152.122 us; speedup vs baseline: 2.2330x; 2.2330x over previous
//
#include <hip/hip_runtime.h>
#include <hip/hip_bf16.h>
#include <stdint.h>

// MHA: B=2, S=2048, D=1024, H=16, dk=64.  All GEMM-shaped work in bf16 MFMA.
// conv->bf16 | QKV gemm (LOG2E/8 in Wq,bq; V transposed [bh][d][s]) |
// flash attn 32x32x16, in-register P (cvt_pk+permlane), no-max softmax,
// KEY-SPLIT x2 across grid (blockIdx.z): each half writes its OWN bf16
// partial-o buffer + f32 partial-l (regular stores, no atomics - r9's
// atomicAdd combine cost 134 MB of L2 RMW traffic) | O-proj gemm with the
// combine fused into A-staging: a = (o0+o1) * 1/(l0+l1) -> bf16 -> f32 out.

#define LOG2E 1.4426950408889634f

typedef float f32x4 __attribute__((ext_vector_type(4)));
typedef float f32x16 __attribute__((ext_vector_type(16)));
typedef short bf16x8 __attribute__((ext_vector_type(8)));
typedef short bf16x4 __attribute__((ext_vector_type(4)));
typedef unsigned int u32x2 __attribute__((ext_vector_type(2)));

__device__ __forceinline__ unsigned short f2bf(float f) {
  __hip_bfloat16 h = __float2bfloat16(f);
  return reinterpret_cast<unsigned short&>(h);
}
__device__ __forceinline__ float bf2f(unsigned short u) {
  union { unsigned int i; float f; } v; v.i = ((unsigned int)u) << 16; return v.f;
}

#define GLDS(g, l) __builtin_amdgcn_global_load_lds(                          \
    (const __attribute__((address_space(1))) void*)(g),                       \
    (__attribute__((address_space(3))) void*)(l), 16, 0, 0)

// ---------- fp32 -> bf16 conversion ----------
__global__ __launch_bounds__(256) void k_conv(const float* __restrict__ src,
                                              unsigned short* __restrict__ dst,
                                              int n4, float scale) {
  int i = blockIdx.x * 256 + threadIdx.x;
  const int stride = gridDim.x * 256;
  for (; i < n4; i += stride) {
    float4 v = ((const float4*)src)[i];
    ushort4 o;
    o.x = f2bf(v.x * scale);
    o.y = f2bf(v.y * scale);
    o.z = f2bf(v.z * scale);
    o.w = f2bf(v.w * scale);
    ((ushort4*)dst)[i] = o;
  }
}

// all 4 weight matrices in one launch; Wq scaled by LOG2E/8
__global__ __launch_bounds__(256) void k_convW(const float* __restrict__ wq,
                                               const float* __restrict__ wk,
                                               const float* __restrict__ wv,
                                               const float* __restrict__ wo,
                                               unsigned short* __restrict__ dq,
                                               unsigned short* __restrict__ dk,
                                               unsigned short* __restrict__ dv,
                                               unsigned short* __restrict__ dw) {
  const int m = blockIdx.y;
  const float* src = (m == 0) ? wq : (m == 1) ? wk : (m == 2) ? wv : wo;
  unsigned short* dst = (m == 0) ? dq : (m == 1) ? dk : (m == 2) ? dv : dw;
  const float scale = (m == 0) ? (0.125f * LOG2E) : 1.0f;
  int i = blockIdx.x * 256 + threadIdx.x;
  float4 v = ((const float4*)src)[i];
  ushort4 o;
  o.x = f2bf(v.x * scale);
  o.y = f2bf(v.y * scale);
  o.z = f2bf(v.z * scale);
  o.w = f2bf(v.w * scale);
  ((ushort4*)dst)[i] = o;
}

// fused bias vector [3072]: bq*LOG2E/8 | bk | bv
__global__ __launch_bounds__(256) void k_bias(const float* __restrict__ bq,
                                              const float* __restrict__ bk,
                                              const float* __restrict__ bv,
                                              float* __restrict__ out) {
  int i = blockIdx.x * 256 + threadIdx.x;
  float v;
  if (i < 1024) v = bq[i] * (0.125f * LOG2E);
  else if (i < 2048) v = bk[i - 1024];
  else v = bv[i - 2048];
  out[i] = v;
}

// ---------- QKV GEMM: C[m][n] = sum_k A[m][k]*B[n][k] + bias[n] ----------
__global__ __launch_bounds__(256) void k_gemm0(const unsigned short* __restrict__ A,
                                               const unsigned short* __restrict__ B,
                                               const float* __restrict__ bias,
                                               unsigned short* __restrict__ outp) {
  __shared__ unsigned short As[128 * 32];
  __shared__ unsigned short Bs[128 * 32];
  const int tid = threadIdx.x;
  const int lane = tid & 63, wid = tid >> 6;
  const int wr = wid >> 1, wc = wid & 1;
  const int r = lane & 15, g = lane >> 4;
  const int bm = blockIdx.x, bn = blockIdx.y;

  const unsigned short* gA = A + (size_t)bm * 128 * 1024;
  const unsigned short* gB = B + (size_t)bn * 128 * 1024;
  const int row0 = tid >> 2, cg = (tid & 3) * 8;

  f32x4 acc[4][4] = {};

  for (int k0 = 0; k0 < 1024; k0 += 32) {
    __syncthreads();
    GLDS(gA + (size_t)row0 * 1024 + k0 + cg,        As + row0 * 32 + cg);
    GLDS(gA + (size_t)(row0 + 64) * 1024 + k0 + cg, As + (row0 + 64) * 32 + cg);
    GLDS(gB + (size_t)row0 * 1024 + k0 + cg,        Bs + row0 * 32 + cg);
    GLDS(gB + (size_t)(row0 + 64) * 1024 + k0 + cg, Bs + (row0 + 64) * 32 + cg);
    __syncthreads();

    bf16x8 af[4], bfr[4];
#pragma unroll
    for (int i = 0; i < 4; i++) {
      af[i]  = *(const bf16x8*)(As + (wr * 64 + i * 16 + r) * 32 + g * 8);
      bfr[i] = *(const bf16x8*)(Bs + (wc * 64 + i * 16 + r) * 32 + g * 8);
    }
#pragma unroll
    for (int i = 0; i < 4; i++)
#pragma unroll
      for (int j = 0; j < 4; j++)
        acc[i][j] = __builtin_amdgcn_mfma_f32_16x16x32_bf16(af[i], bfr[j], acc[i][j], 0, 0, 0);
  }

#pragma unroll
  for (int i = 0; i < 4; i++) {
    const int rowb = bm * 128 + wr * 64 + i * 16 + g * 4;
#pragma unroll
    for (int j = 0; j < 4; j++) {
      const int col = bn * 128 + wc * 64 + j * 16 + r;
      const float bv = bias[col];
#pragma unroll
      for (int t = 0; t < 4; t++) {
        const int row = rowb + t;
        const float val = acc[i][j][t] + bv;
        const int mat = col >> 10, nn = col & 1023;
        const int hh = nn >> 6, dd = nn & 63;
        const int bb = row >> 11, ss = row & 2047;
        size_t idx;
        if (mat == 2)  // V transposed: [bh][d][s]
          idx = (size_t)2 * 4194304 + (size_t)((bb * 16 + hh) * 64 + dd) * 2048 + ss;
        else
          idx = (size_t)mat * 4194304 + (size_t)((bb * 16 + hh) * 2048 + ss) * 64 + dd;
        outp[idx] = f2bf(val);
      }
    }
  }
}

// ---------- O-proj GEMM with fused key-split combine ----------
// A[row][k] = (oP0[row][k] + oP1[row][k]) / (l0[b,h(k),s] + l1[b,h(k),s])
__global__ __launch_bounds__(256) void k_gemm1(const unsigned short* __restrict__ oP,
                                               const float* __restrict__ lP,
                                               const unsigned short* __restrict__ Bw,
                                               const float* __restrict__ bias,
                                               float* __restrict__ outp) {
  __shared__ unsigned short As[128 * 32];
  __shared__ unsigned short Bs[128 * 32];
  const int tid = threadIdx.x;
  const int lane = tid & 63, wid = tid >> 6;
  const int wr = wid >> 1, wc = wid & 1;
  const int r = lane & 15, g = lane >> 4;
  const int bm = blockIdx.x, bn = blockIdx.y;

  const unsigned short* gB = Bw + (size_t)bn * 128 * 1024;
  const int row0 = tid >> 2, cg = (tid & 3) * 8;
  const int gr0 = bm * 128 + row0, gr1 = gr0 + 64;
  const int s0g = gr0 & 2047, b0g = gr0 >> 11;
  const int s1g = gr1 & 2047, b1g = gr1 >> 11;
  const unsigned short* A0 = oP;
  const unsigned short* A1 = oP + 4194304;

  f32x4 acc[4][4] = {};

  for (int k0 = 0; k0 < 1024; k0 += 32) {
    const int hh = (k0 + cg) >> 6;
    const int li0 = (b0g * 16 + hh) * 2048 + s0g;
    const int li1 = (b1g * 16 + hh) * 2048 + s1g;
    const float inv0 = 1.0f / (lP[li0] + lP[65536 + li0]);
    const float inv1 = 1.0f / (lP[li1] + lP[65536 + li1]);
    const bf16x8 x00 = *(const bf16x8*)(A0 + (size_t)gr0 * 1024 + k0 + cg);
    const bf16x8 x01 = *(const bf16x8*)(A1 + (size_t)gr0 * 1024 + k0 + cg);
    const bf16x8 x10 = *(const bf16x8*)(A0 + (size_t)gr1 * 1024 + k0 + cg);
    const bf16x8 x11 = *(const bf16x8*)(A1 + (size_t)gr1 * 1024 + k0 + cg);
    __syncthreads();
    GLDS(gB + (size_t)row0 * 1024 + k0 + cg,        Bs + row0 * 32 + cg);
    GLDS(gB + (size_t)(row0 + 64) * 1024 + k0 + cg, Bs + (row0 + 64) * 32 + cg);
    bf16x8 pa0, pa1;
#pragma unroll
    for (int j = 0; j < 8; j++) {
      pa0[j] = (short)f2bf((bf2f((unsigned short)x00[j]) + bf2f((unsigned short)x01[j])) * inv0);
      pa1[j] = (short)f2bf((bf2f((unsigned short)x10[j]) + bf2f((unsigned short)x11[j])) * inv1);
    }
    *(bf16x8*)(As + row0 * 32 + cg) = pa0;
    *(bf16x8*)(As + (row0 + 64) * 32 + cg) = pa1;
    __syncthreads();

    bf16x8 af[4], bfr[4];
#pragma unroll
    for (int i = 0; i < 4; i++) {
      af[i]  = *(const bf16x8*)(As + (wr * 64 + i * 16 + r) * 32 + g * 8);
      bfr[i] = *(const bf16x8*)(Bs + (wc * 64 + i * 16 + r) * 32 + g * 8);
    }
#pragma unroll
    for (int i = 0; i < 4; i++)
#pragma unroll
      for (int j = 0; j < 4; j++)
        acc[i][j] = __builtin_amdgcn_mfma_f32_16x16x32_bf16(af[i], bfr[j], acc[i][j], 0, 0, 0);
  }

#pragma unroll
  for (int i = 0; i < 4; i++) {
    const int rowb = bm * 128 + wr * 64 + i * 16 + g * 4;
#pragma unroll
    for (int j = 0; j < 4; j++) {
      const int col = bn * 128 + wc * 64 + j * 16 + r;
      const float bv = bias[col];
#pragma unroll
      for (int t = 0; t < 4; t++)
        outp[(size_t)(rowb + t) * 1024 + col] = acc[i][j][t] + bv;
    }
  }
}

// ---------- flash attention (32x32 MFMA, grid key-split x2, no atomics) ----
// grid (16 q-tiles of 128, 32 b*h, 2 key-halves) = 1024 blocks = 4/CU.
// 256 thd = 4 waves; wave w owns q-rows q0+w*32+(lane&31); block covers keys
// kg*1024..+1023 (16 tiles of 64).  Per 32-key subtile: 4 QK MFMA (setprio1)
// -> 16 exp2 -> 8 cvt_pk + 4 permlane32_swap -> 4 PV MFMA (setprio1).
// Epilogue: REGULAR stores of bf16 partial o into oPart[kg] and f32 partial
// l into lPart[kg] (single writer per element).
__global__ __launch_bounds__(256) void k_attn(const unsigned short* __restrict__ Q,
                                              const unsigned short* __restrict__ Km,
                                              const unsigned short* __restrict__ Vt,
                                              unsigned short* __restrict__ oPart,
                                              float* __restrict__ lPart) {
  __shared__ unsigned short Kb[2][4096];
  __shared__ unsigned short Vb[2][4096];
  const int tid = threadIdx.x;
  const int lane = tid & 63, w = tid >> 6;
  const int l31 = lane & 31, hi = lane >> 5;
  const int bh = blockIdx.y;
  const int b = bh >> 4, h = bh & 15;
  const int q0 = blockIdx.x * 128;
  const int kg = blockIdx.z;

  const unsigned short* Qh  = Q  + (size_t)bh * 131072;                       // [s][d]
  const unsigned short* KhG = Km + (size_t)bh * 131072 + (size_t)kg * 65536;  // [s][d]
  const unsigned short* VtG = Vt + (size_t)bh * 131072 + 1024 * kg;           // [d][s]

  const int qrow = q0 + w * 32 + l31;
  bf16x8 bQ[4];
#pragma unroll
  for (int c = 0; c < 4; c++)
    bQ[c] = *(const bf16x8*)(Qh + (size_t)qrow * 64 + c * 16 + hi * 8);

  // staging source perms (chunk id = op*256+tid -> (s, c, l2))
  int ksrc[2], vsrc[2];
#pragma unroll
  for (int op = 0; op < 2; op++) {
    const int ck = op * 256 + tid;
    const int s = ck >> 8, c = (ck >> 6) & 3, l2 = ck & 63;
    ksrc[op] = (s * 32 + (l2 & 31)) * 64 + c * 16 + (l2 >> 5) * 8;
    vsrc[op] = (s * 32 + (l2 & 31)) * 2048 + c * 16 + (l2 >> 5) * 8;
  }
  const int ldst = tid * 8;

  GLDS(KhG + ksrc[0], &Kb[0][ldst]);
  GLDS(KhG + ksrc[1], &Kb[0][2048 + ldst]);
  GLDS(VtG + vsrc[0], &Vb[0][ldst]);
  GLDS(VtG + vsrc[1], &Vb[0][2048 + ldst]);
  __syncthreads();

  f32x16 o0 = {0.f,0.f,0.f,0.f,0.f,0.f,0.f,0.f,0.f,0.f,0.f,0.f,0.f,0.f,0.f,0.f};
  f32x16 o1 = o0;
  float lsum = 0.f;

  for (int t = 0; t < 16; ++t) {
    const int cur = t & 1;
    if (t < 15) {
      const size_t kv = (size_t)(t + 1) * 64;
      GLDS(KhG + kv * 64 + ksrc[0], &Kb[cur ^ 1][ldst]);
      GLDS(KhG + kv * 64 + ksrc[1], &Kb[cur ^ 1][2048 + ldst]);
      GLDS(VtG + kv + vsrc[0], &Vb[cur ^ 1][ldst]);
      GLDS(VtG + kv + vsrc[1], &Vb[cur ^ 1][2048 + ldst]);
    }

    const unsigned short* kb = &Kb[cur][0];
    const unsigned short* vb = &Vb[cur][0];

#define SUBTILE(SC)                                                            \
    {                                                                          \
      bf16x8 kf0 = *(const bf16x8*)(kb + (((SC)*4 + 0) * 64 + lane) * 8);      \
      bf16x8 kf1 = *(const bf16x8*)(kb + (((SC)*4 + 1) * 64 + lane) * 8);      \
      bf16x8 kf2 = *(const bf16x8*)(kb + (((SC)*4 + 2) * 64 + lane) * 8);      \
      bf16x8 kf3 = *(const bf16x8*)(kb + (((SC)*4 + 3) * 64 + lane) * 8);      \
      f32x16 St = {0.f,0.f,0.f,0.f,0.f,0.f,0.f,0.f,                            \
                   0.f,0.f,0.f,0.f,0.f,0.f,0.f,0.f};                           \
      __builtin_amdgcn_s_setprio(1);                                           \
      St = __builtin_amdgcn_mfma_f32_32x32x16_bf16(kf0, bQ[0], St, 0, 0, 0);   \
      St = __builtin_amdgcn_mfma_f32_32x32x16_bf16(kf1, bQ[1], St, 0, 0, 0);   \
      St = __builtin_amdgcn_mfma_f32_32x32x16_bf16(kf2, bQ[2], St, 0, 0, 0);   \
      St = __builtin_amdgcn_mfma_f32_32x32x16_bf16(kf3, bQ[3], St, 0, 0, 0);   \
      __builtin_amdgcn_s_setprio(0);                                           \
      float p[16];                                                             \
      float ps = 0.f;                                                          \
      _Pragma("unroll")                                                        \
      for (int u = 0; u < 16; u++) {                                           \
        p[u] = __builtin_amdgcn_exp2f(St[u]);                                  \
        ps += p[u];                                                            \
      }                                                                        \
      lsum += ps;                                                              \
      unsigned int a0, a1, b0, b1;                                             \
      asm("v_cvt_pk_bf16_f32 %0, %1, %2" : "=v"(a0) : "v"(p[0]), "v"(p[1]));   \
      asm("v_cvt_pk_bf16_f32 %0, %1, %2" : "=v"(a1) : "v"(p[2]), "v"(p[3]));   \
      asm("v_cvt_pk_bf16_f32 %0, %1, %2" : "=v"(b0) : "v"(p[4]), "v"(p[5]));   \
      asm("v_cvt_pk_bf16_f32 %0, %1, %2" : "=v"(b1) : "v"(p[6]), "v"(p[7]));   \
      u32x2 r0 = __builtin_amdgcn_permlane32_swap(a0, b0, false, false);       \
      u32x2 r1 = __builtin_amdgcn_permlane32_swap(a1, b1, false, false);       \
      union { unsigned int u[4]; bf16x8 v; } pfE;                              \
      pfE.u[0] = r0[0]; pfE.u[1] = r1[0]; pfE.u[2] = r0[1]; pfE.u[3] = r1[1];  \
      asm("v_cvt_pk_bf16_f32 %0, %1, %2" : "=v"(a0) : "v"(p[8]), "v"(p[9]));   \
      asm("v_cvt_pk_bf16_f32 %0, %1, %2" : "=v"(a1) : "v"(p[10]), "v"(p[11])); \
      asm("v_cvt_pk_bf16_f32 %0, %1, %2" : "=v"(b0) : "v"(p[12]), "v"(p[13])); \
      asm("v_cvt_pk_bf16_f32 %0, %1, %2" : "=v"(b1) : "v"(p[14]), "v"(p[15])); \
      r0 = __builtin_amdgcn_permlane32_swap(a0, b0, false, false);             \
      r1 = __builtin_amdgcn_permlane32_swap(a1, b1, false, false);             \
      union { unsigned int u[4]; bf16x8 v; } pfO;                              \
      pfO.u[0] = r0[0]; pfO.u[1] = r1[0]; pfO.u[2] = r0[1]; pfO.u[3] = r1[1];  \
      bf16x8 v00 = *(const bf16x8*)(vb + ((0 + 2*(SC)) * 64 + lane) * 8);      \
      bf16x8 v01 = *(const bf16x8*)(vb + ((1 + 2*(SC)) * 64 + lane) * 8);      \
      bf16x8 v10 = *(const bf16x8*)(vb + ((4 + 2*(SC)) * 64 + lane) * 8);      \
      bf16x8 v11 = *(const bf16x8*)(vb + ((5 + 2*(SC)) * 64 + lane) * 8);      \
      __builtin_amdgcn_s_setprio(1);                                           \
      o0 = __builtin_amdgcn_mfma_f32_32x32x16_bf16(v00, pfE.v, o0, 0, 0, 0);   \
      o0 = __builtin_amdgcn_mfma_f32_32x32x16_bf16(v01, pfO.v, o0, 0, 0, 0);   \
      o1 = __builtin_amdgcn_mfma_f32_32x32x16_bf16(v10, pfE.v, o1, 0, 0, 0);   \
      o1 = __builtin_amdgcn_mfma_f32_32x32x16_bf16(v11, pfO.v, o1, 0, 0, 0);   \
      __builtin_amdgcn_s_setprio(0);                                           \
    }

    SUBTILE(0)
    SUBTILE(1)
#undef SUBTILE

    __syncthreads();   // drains stage vmcnt + protects buffer reuse
  }

  // epilogue: regular stores of partials.  d = ds*32+(u&3)+8*(u>>2)+4*hi.
  const float lrow = lsum + __shfl_xor(lsum, 32);
  if (hi == 0) lPart[kg * 65536 + bh * 2048 + qrow] = lrow;
  unsigned short* oP = oPart + (size_t)kg * 4194304 +
                       (size_t)(b * 2048 + qrow) * 1024 + h * 64;
#pragma unroll
  for (int ds = 0; ds < 2; ds++) {
    const f32x16& oo = ds ? o1 : o0;
#pragma unroll
    for (int m = 0; m < 4; m++) {
      bf16x4 ov;
#pragma unroll
      for (int i = 0; i < 4; i++) ov[i] = (short)f2bf(oo[m * 4 + i]);
      *(bf16x4*)(oP + ds * 32 + m * 8 + hi * 4) = ov;
    }
  }
}

extern "C" void kernel_launch(void* const* d_in, const int* in_sizes, int n_in,
                              void* d_out, int out_size, void* d_ws, size_t ws_size,
                              hipStream_t stream) {
  const float* x  = (const float*)d_in[0];
  const float* Wq = (const float*)d_in[1];
  const float* bq = (const float*)d_in[2];
  const float* Wk = (const float*)d_in[3];
  const float* bk = (const float*)d_in[4];
  const float* Wv = (const float*)d_in[5];
  const float* bv = (const float*)d_in[6];
  const float* Wo = (const float*)d_in[7];
  const float* bo = (const float*)d_in[8];

  if (ws_size < (size_t)44576768) return;

  unsigned short* ws  = (unsigned short*)d_ws;
  unsigned short* qkv  = ws;                       // Q|K [32][2048][64]; Vt [32][64][2048]
  unsigned short* Wob  = ws + 12582912;            // Wo bf16 [1024][1024]
  float* biasQ = (float*)(ws + 13631488);          // fused qkv bias [3072]
  float* lPart = (float*)(ws + 13637632);          // partial l [2][32][2048]
  unsigned short* oPart = ws + 13899776;           // partial o bf16 [2][4096][1024]
  unsigned short* xb = ws + 13899776;              // x bf16 (overlays oPart; dead
  unsigned short* Wb = ws + 18094080;              //  after gemm0, as is Wb)

  k_conv<<<dim3(2048), dim3(256), 0, stream>>>(x, xb, 1048576, 1.0f);
  k_convW<<<dim3(1024, 4), dim3(256), 0, stream>>>(Wq, Wk, Wv, Wo,
      Wb, Wb + 1048576, Wb + 2097152, Wob);
  k_bias<<<dim3(12), dim3(256), 0, stream>>>(bq, bk, bv, biasQ);

  k_gemm0<<<dim3(32, 24), dim3(256), 0, stream>>>(xb, Wb, biasQ, qkv);
  k_attn<<<dim3(16, 32, 2), dim3(256), 0, stream>>>(
      qkv, qkv + 4194304, qkv + 8388608, oPart, lPart);
  k_gemm1<<<dim3(32, 8), dim3(256), 0, stream>>>(oPart, lPart, Wob, bo, (float*)d_out);
}